// Round 1
// baseline (3787.006 us; speedup 1.0000x reference)
//
#include <hip/hip_runtime.h>
#include <cstdint>
#include <cstddef>

namespace {
constexpr int B_ = 4, S_ = 2048, D_ = 1024, H_ = 16, DK_ = 64;
constexpr int N_ = H_ * DK_;   // 1024
constexpr int M_ = B_ * S_;    // 8192
}

// ---------------------------------------------------------------------------
// Generic 64x64-tile fp32 GEMM: C = A[M,1024] @ W[1024,1024] + bias[1024]
// MODE 0: C row-major [M, 1024]
// MODE 1: C scattered to [B, H, S, DK]  (n -> (h,d), m -> (b,s))
// block = 256 threads (16x16), each thread computes 4x4; K-tile = 16
// ---------------------------------------------------------------------------
template <int MODE>
__global__ __launch_bounds__(256) void k_gemm(
    const float* __restrict__ A, const float* __restrict__ W,
    const float* __restrict__ bias, float* __restrict__ C)
{
    __shared__ float As[64][17];
    __shared__ float Bs[16][68];
    const int tid = threadIdx.x;
    const int tx = tid & 15, ty = tid >> 4;
    const int n0 = blockIdx.x * 64, m0 = blockIdx.y * 64;
    const int arow = tid >> 2, ac4 = (tid & 3) * 4;
    const int brow = tid >> 4, bc4 = (tid & 15) * 4;
    float acc[4][4] = {};
    for (int k0 = 0; k0 < D_; k0 += 16) {
        float4 av = *(const float4*)(A + (size_t)(m0 + arow) * D_ + (k0 + ac4));
        float4 bv = *(const float4*)(W + (size_t)(k0 + brow) * N_ + (n0 + bc4));
        As[arow][ac4 + 0] = av.x; As[arow][ac4 + 1] = av.y;
        As[arow][ac4 + 2] = av.z; As[arow][ac4 + 3] = av.w;
        Bs[brow][bc4 + 0] = bv.x; Bs[brow][bc4 + 1] = bv.y;
        Bs[brow][bc4 + 2] = bv.z; Bs[brow][bc4 + 3] = bv.w;
        __syncthreads();
        #pragma unroll
        for (int kk = 0; kk < 16; ++kk) {
            float a_[4] = {As[ty][kk], As[ty + 16][kk], As[ty + 32][kk], As[ty + 48][kk]};
            float b_[4] = {Bs[kk][tx], Bs[kk][tx + 16], Bs[kk][tx + 32], Bs[kk][tx + 48]};
            #pragma unroll
            for (int i = 0; i < 4; ++i)
                #pragma unroll
                for (int j = 0; j < 4; ++j)
                    acc[i][j] = fmaf(a_[i], b_[j], acc[i][j]);
        }
        __syncthreads();
    }
    #pragma unroll
    for (int i = 0; i < 4; ++i) {
        int m = m0 + ty + 16 * i;
        #pragma unroll
        for (int j = 0; j < 4; ++j) {
            int n = n0 + tx + 16 * j;
            float cv = acc[i][j] + bias[n];
            if (MODE == 0) {
                C[(size_t)m * N_ + n] = cv;
            } else {
                int b = m >> 11, s = m & (S_ - 1);
                int h = n >> 6, d = n & (DK_ - 1);
                C[(((size_t)(b * H_ + h)) * S_ + s) * DK_ + d] = cv;
            }
        }
    }
}

// ---------------------------------------------------------------------------
// Raw scores: Sc[bh, q, k] = (Q[bh,q,:] . K[bh,k,:]) / 8    (no mask yet)
// grid = (S/64, S/64, B*H), 64x64 tile, K-dim = 64
// ---------------------------------------------------------------------------
__global__ __launch_bounds__(256) void k_qkt(
    const float* __restrict__ Q, const float* __restrict__ K,
    float* __restrict__ Sc)
{
    __shared__ float As[64][17];
    __shared__ float Bs[16][68];
    const int tid = threadIdx.x;
    const int tx = tid & 15, ty = tid >> 4;
    const int bh = blockIdx.z;
    const float* Qm = Q + (size_t)bh * S_ * DK_;
    const float* Km = K + (size_t)bh * S_ * DK_;
    float* Cm = Sc + (size_t)bh * S_ * S_;
    const int n0 = blockIdx.x * 64, m0 = blockIdx.y * 64;
    const int arow = tid >> 2, ac4 = (tid & 3) * 4;
    float acc[4][4] = {};
    for (int k0 = 0; k0 < DK_; k0 += 16) {
        float4 av = *(const float4*)(Qm + (size_t)(m0 + arow) * DK_ + (k0 + ac4));
        float4 bv = *(const float4*)(Km + (size_t)(n0 + arow) * DK_ + (k0 + ac4));
        As[arow][ac4 + 0] = av.x; As[arow][ac4 + 1] = av.y;
        As[arow][ac4 + 2] = av.z; As[arow][ac4 + 3] = av.w;
        // transpose K tile into Bs[kk][n]
        Bs[ac4 + 0][arow] = bv.x; Bs[ac4 + 1][arow] = bv.y;
        Bs[ac4 + 2][arow] = bv.z; Bs[ac4 + 3][arow] = bv.w;
        __syncthreads();
        #pragma unroll
        for (int kk = 0; kk < 16; ++kk) {
            float a_[4] = {As[ty][kk], As[ty + 16][kk], As[ty + 32][kk], As[ty + 48][kk]};
            float b_[4] = {Bs[kk][tx], Bs[kk][tx + 16], Bs[kk][tx + 32], Bs[kk][tx + 48]};
            #pragma unroll
            for (int i = 0; i < 4; ++i)
                #pragma unroll
                for (int j = 0; j < 4; ++j)
                    acc[i][j] = fmaf(a_[i], b_[j], acc[i][j]);
        }
        __syncthreads();
    }
    #pragma unroll
    for (int i = 0; i < 4; ++i) {
        int m = m0 + ty + 16 * i;
        #pragma unroll
        for (int j = 0; j < 4; ++j) {
            int n = n0 + tx + 16 * j;
            Cm[(size_t)m * S_ + n] = acc[i][j] * 0.125f;
        }
    }
}

// ---------------------------------------------------------------------------
// In-place masked softmax over the last dim of Sc [B*H, S, S]
// one block (256 threads) per row; each thread owns 8 columns
// ---------------------------------------------------------------------------
__device__ inline float wred_max(float v) {
    #pragma unroll
    for (int o = 32; o > 0; o >>= 1) v = fmaxf(v, __shfl_xor(v, o));
    return v;
}
__device__ inline float wred_sum(float v) {
    #pragma unroll
    for (int o = 32; o > 0; o >>= 1) v += __shfl_xor(v, o);
    return v;
}

__global__ __launch_bounds__(256) void k_softmax(
    float* __restrict__ Sc, const int* __restrict__ mask)
{
    const int qi = blockIdx.x, h = blockIdx.y, b = blockIdx.z;
    float* row = Sc + (((size_t)(b * H_ + h)) * S_ + qi) * S_;
    const int* mrow = mask + (size_t)b * S_;
    const int t = threadIdx.x;
    __shared__ float redm[4];
    __shared__ float reds[4];

    float sc[8];
    float mx = -1e30f;
    #pragma unroll
    for (int c = 0; c < 8; ++c) {
        int col = c * 256 + t;
        float sv = row[col];
        if (mrow[col] == 0) sv = -1e10f;
        sc[c] = sv;
        mx = fmaxf(mx, sv);
    }
    float wm = wred_max(mx);
    if ((t & 63) == 0) redm[t >> 6] = wm;
    __syncthreads();
    float gmax = fmaxf(fmaxf(redm[0], redm[1]), fmaxf(redm[2], redm[3]));

    float sum = 0.f;
    #pragma unroll
    for (int c = 0; c < 8; ++c) {
        sc[c] = __expf(sc[c] - gmax);
        sum += sc[c];
    }
    float ws = wred_sum(sum);
    if ((t & 63) == 0) reds[t >> 6] = ws;
    __syncthreads();
    float gsum = reds[0] + reds[1] + reds[2] + reds[3];
    float inv = 1.0f / gsum;
    #pragma unroll
    for (int c = 0; c < 8; ++c)
        row[c * 256 + t] = sc[c] * inv;
}

// ---------------------------------------------------------------------------
// X[b, s, h*64+d] = sum_k P[bh, s, k] * V[bh, k, d]
// grid = (1, S/64, B*H); 64 rows x 64 cols per block; K-tile = 16 over 2048
// ---------------------------------------------------------------------------
__global__ __launch_bounds__(256) void k_pv(
    const float* __restrict__ P, const float* __restrict__ V,
    float* __restrict__ X)
{
    __shared__ float As[64][17];
    __shared__ float Bs[16][68];
    const int tid = threadIdx.x;
    const int tx = tid & 15, ty = tid >> 4;
    const int bh = blockIdx.z;
    const int b = bh >> 4, h = bh & 15;
    const float* Pm = P + (size_t)bh * S_ * S_;
    const float* Vm = V + (size_t)bh * S_ * DK_;
    const int m0 = blockIdx.y * 64;
    const int arow = tid >> 2, ac4 = (tid & 3) * 4;
    const int brow = tid >> 4, bc4 = (tid & 15) * 4;
    float acc[4][4] = {};
    for (int k0 = 0; k0 < S_; k0 += 16) {
        float4 av = *(const float4*)(Pm + (size_t)(m0 + arow) * S_ + (k0 + ac4));
        float4 bv = *(const float4*)(Vm + (size_t)(k0 + brow) * DK_ + bc4);
        As[arow][ac4 + 0] = av.x; As[arow][ac4 + 1] = av.y;
        As[arow][ac4 + 2] = av.z; As[arow][ac4 + 3] = av.w;
        Bs[brow][bc4 + 0] = bv.x; Bs[brow][bc4 + 1] = bv.y;
        Bs[brow][bc4 + 2] = bv.z; Bs[brow][bc4 + 3] = bv.w;
        __syncthreads();
        #pragma unroll
        for (int kk = 0; kk < 16; ++kk) {
            float a_[4] = {As[ty][kk], As[ty + 16][kk], As[ty + 32][kk], As[ty + 48][kk]};
            float b_[4] = {Bs[kk][tx], Bs[kk][tx + 16], Bs[kk][tx + 32], Bs[kk][tx + 48]};
            #pragma unroll
            for (int i = 0; i < 4; ++i)
                #pragma unroll
                for (int j = 0; j < 4; ++j)
                    acc[i][j] = fmaf(a_[i], b_[j], acc[i][j]);
        }
        __syncthreads();
    }
    #pragma unroll
    for (int i = 0; i < 4; ++i) {
        int s = m0 + ty + 16 * i;
        #pragma unroll
        for (int j = 0; j < 4; ++j) {
            int d = tx + 16 * j;
            X[((size_t)(b * S_ + s)) * N_ + h * DK_ + d] = acc[i][j];
        }
    }
}

// ---------------------------------------------------------------------------
extern "C" void kernel_launch(void* const* d_in, const int* in_sizes, int n_in,
                              void* d_out, int out_size, void* d_ws, size_t ws_size,
                              hipStream_t stream)
{
    const float* q    = (const float*)d_in[0];
    const float* k    = (const float*)d_in[1];
    const float* v    = (const float*)d_in[2];
    const int*   mask = (const int*)d_in[3];
    const float* wq   = (const float*)d_in[4];
    const float* bq   = (const float*)d_in[5];
    const float* wk   = (const float*)d_in[6];
    const float* bk   = (const float*)d_in[7];
    const float* wv   = (const float*)d_in[8];
    const float* bv   = (const float*)d_in[9];
    const float* wo   = (const float*)d_in[10];
    const float* bo   = (const float*)d_in[11];

    float* out = (float*)d_out;                           // [B,S,D]  8M floats
    float* sim = out + (size_t)B_ * S_ * D_;              // [B,H,S,S] 256M floats

    float* Q = (float*)d_ws;                              // [B,H,S,DK] 8M floats
    float* K = Q + (size_t)M_ * N_;                       // +8M
    float* V = K + (size_t)M_ * N_;                       // +8M
    float* X = Q;                                         // Q is dead after k_qkt

    dim3 blk(256);
    dim3 gProj(N_ / 64, M_ / 64, 1);      // (16,128)
    k_gemm<1><<<gProj, blk, 0, stream>>>(q, wq, bq, Q);
    k_gemm<1><<<gProj, blk, 0, stream>>>(k, wk, bk, K);
    k_gemm<1><<<gProj, blk, 0, stream>>>(v, wv, bv, V);

    dim3 gQK(S_ / 64, S_ / 64, B_ * H_);  // (32,32,64)
    k_qkt<<<gQK, blk, 0, stream>>>(Q, K, sim);

    dim3 gSm(S_, H_, B_);                 // (2048,16,4)
    k_softmax<<<gSm, blk, 0, stream>>>(sim, mask);

    dim3 gPV(1, S_ / 64, B_ * H_);        // (1,32,64)
    k_pv<<<gPV, blk, 0, stream>>>(sim, V, X);

    k_gemm<0><<<gProj, blk, 0, stream>>>(X, wo, bo, out);
}